// Round 11
// baseline (292.403 us; speedup 1.0000x reference)
//
#include <hip/hip_runtime.h>
#include <hip/hip_bf16.h>
#include <math.h>

#define BQ 32
#define SQ 2048
#define DQ 1024
#define NQ 512
#define MQ (BQ*SQ)
#define BM 64
#define BN 512
#define BK 32

typedef __attribute__((ext_vector_type(8))) short bf16x8;
typedef __attribute__((ext_vector_type(4))) short bf16x4;
typedef __attribute__((ext_vector_type(4))) float f32x4;

// compiler-path f32->bf16 (RTNE, pairs into v_cvt_pk_bf16_f32)
__device__ __forceinline__ short f2bf(float f){
  return __builtin_bit_cast(short, __float2bfloat16(f));
}

__device__ __forceinline__ void gload_lds16(const void* g, void* l){
  __builtin_amdgcn_global_load_lds(
      (const __attribute__((address_space(1))) unsigned int*)g,
      (__attribute__((address_space(3))) unsigned int*)l, 16, 0, 0);
}

// ---- prep: transpose gate_w1 [K=1024][N=512] -> bf16 w1t [N=512][K=1024]
__global__ void k_w1t(const float* __restrict__ w1, short* __restrict__ w1t){
  int i = blockIdx.x*256 + threadIdx.x;
  if (i >= NQ*DQ) return;
  int n = i >> 10, k = i & (DQ-1);
  w1t[i] = f2bf(w1[(size_t)k*NQ + n]);
}

// ---- prep: wq[d] = key_w[d,:]·q (d<1024); wq[1024] = key_b·q
__global__ void k_wq(const float* __restrict__ kw, const float* __restrict__ kb,
                     const float* __restrict__ q, float* __restrict__ wq){
  __shared__ float sh[4];
  int d = blockIdx.x, t = threadIdx.x;
  const float* row = (d < DQ) ? (kw + (size_t)d*DQ) : kb;
  float s = 0.f;
  for (int e=t;e<DQ;e+=256) s += row[e]*q[e];
  #pragma unroll
  for (int o=32;o;o>>=1) s += __shfl_down(s,o);
  if ((t&63)==0) sh[t>>6]=s;
  __syncthreads();
  if (t==0) wq[d] = sh[0]+sh[1]+sh[2]+sh[3];
}

// ---- prep: xbf = bf16(x); xqv[r] = x[r]·wq   (x in regs once)
__global__ __launch_bounds__(256) void k_xprep(
    const float* __restrict__ x, const float* __restrict__ wq,
    short* __restrict__ xbf, float* __restrict__ xqv)
{
  __shared__ float sh[4];
  int t = threadIdx.x;
  int r = blockIdx.x*2 + (t>>7);
  int seg = (t & 127) * 8;
  const float* xr = x + (size_t)r*DQ + seg;
  f32x4 a = *(const f32x4*)(xr);
  f32x4 b = *(const f32x4*)(xr + 4);
  f32x4 wa = *(const f32x4*)(wq + seg);
  f32x4 wb = *(const f32x4*)(wq + seg + 4);
  float s = a[0]*wa[0]+a[1]*wa[1]+a[2]*wa[2]+a[3]*wa[3]
          + b[0]*wb[0]+b[1]*wb[1]+b[2]*wb[2]+b[3]*wb[3];
  bf16x8 sv;
  #pragma unroll
  for (int j=0;j<4;j++){ sv[j]=f2bf(a[j]); sv[4+j]=f2bf(b[j]); }
  *(bf16x8*)(xbf + (size_t)r*DQ + seg) = sv;
  #pragma unroll
  for (int o=1;o<64;o<<=1) s += __shfl_xor(s,o);
  if ((t&63)==0) sh[t>>6]=s;
  __syncthreads();
  if ((t&127)==0) xqv[r] = sh[(t>>7)*2] + sh[(t>>7)*2+1];
}

// ---- mask dtype detector: 0=int32(0/1), 1=float32(0/1.0f), 2=byte(bool)
__global__ void k_det(const unsigned int* __restrict__ m, int* __restrict__ flag){
  __shared__ int so, sf;
  int t = threadIdx.x;
  if (t==0){ so=0; sf=0; }
  __syncthreads();
  int o=0, f1=0;
  for (int i=t;i<MQ/4;i+=256){
    unsigned v = m[i];
    if (v==0x3F800000u) f1=1;
    else if (v>1u) o=1;
  }
  if (o) atomicOr(&so,1);
  if (f1) atomicOr(&sf,1);
  __syncthreads();
  if (t==0) *flag = so?2:(sf?1:0);
}

// ---- per-batch valid length
__global__ __launch_bounds__(256) void k_len(const void* __restrict__ maskp,
                                             const int* __restrict__ flag,
                                             int* __restrict__ lens){
  __shared__ int sh[4];
  int b = blockIdx.x, t = threadIdx.x;
  int fl = *flag;
  const unsigned char* m8 = (const unsigned char*)maskp;
  const float* mf = (const float*)maskp;
  const int* mi = (const int*)maskp;
  int cnt = 0;
  #pragma unroll
  for (int i=0;i<8;i++){
    size_t idx = (size_t)b*SQ + t + i*256;
    int mm = (fl==2) ? (m8[idx]!=0) : (fl==1) ? (mf[idx]!=0.0f) : (mi[idx]!=0);
    cnt += mm^1;
  }
  #pragma unroll
  for (int o=32;o;o>>=1) cnt += __shfl_down(cnt,o);
  if ((t&63)==0) sh[t>>6]=cnt;
  __syncthreads();
  if (t==0) lens[b] = sh[0]+sh[1]+sh[2]+sh[3];
}

// ---- shared epilogue device code -------------------------------------------
__device__ __forceinline__ void gate_epilogue(
    int tid, int wid, int lo, int hi, int bm, int m0, int batch, int sBase,
    const f32x4 acc[4][4], const float* w2v, const float* b1v,
    float (*red)[BM], float* wrow,
    const float* __restrict__ xqv, const float* __restrict__ wq,
    const float* __restrict__ b2p, const float* __restrict__ lamp,
    const void* __restrict__ maskp, const int* __restrict__ flag,
    const int* __restrict__ lens,
    const float* __restrict__ x, float* __restrict__ part,
    float* __restrict__ wsum)
{
  #pragma unroll
  for (int fm=0;fm<4;fm++){
    #pragma unroll
    for (int j=0;j<4;j++){
      float s = 0.f;
      #pragma unroll
      for (int fn=0;fn<4;fn++){
        float h = acc[fm][fn][j] + b1v[fn];
        float g = 0.5f*h*(1.0f + erff(h*0.70710678118f));
        s += g*w2v[fn];
      }
      s += __shfl_xor(s,1); s += __shfl_xor(s,2);
      s += __shfl_xor(s,4); s += __shfl_xor(s,8);
      if (lo == 0) red[wid][fm*16 + hi*4 + j] = s;
    }
  }
  __syncthreads();

  if (tid < 64){
    int s = sBase + tid;
    float gsum = b2p[0];
    #pragma unroll
    for (int w=0;w<8;w++) gsum += red[w][tid];
    float gate = 1.0f/(1.0f+expf(-gsum));
    float qb = wq[DQ];
    float lg = (gate*xqv[m0 + tid] + qb)*0.03125f;
    float lam = lamp[0];
    float posl = fmaxf(lam,0.f) + log1pf(expf(-fabsf(lam)));
    int L = lens[batch];
    float pen = fmaxf((float)L - 1.0f - (float)s, 0.0f);
    int fl = *flag;
    size_t mi_ = (size_t)batch*SQ + s;
    int mm = (fl==2) ? (((const unsigned char*)maskp)[mi_]!=0)
           : (fl==1) ? (((const float*)maskp)[mi_]!=0.0f)
                     : (((const int*)maskp)[mi_]!=0);
    float e = mm ? 0.0f : expf(lg - posl*pen);
    wrow[tid] = e*gate;
    float tsum = e;
    #pragma unroll
    for (int o=1;o<64;o<<=1) tsum += __shfl_xor(tsum,o);
    if (tid==0) wsum[bm] = tsum;
  }
  __syncthreads();

  {
    int d0 = tid*2;
    const float* xb = x + (size_t)m0*DQ + d0;
    float a0=0.f, a1=0.f;
    #pragma unroll 8
    for (int s=0;s<64;s++){
      float w = wrow[s];
      float2 v = *(const float2*)(xb + (size_t)s*DQ);
      a0 += w*v.x; a1 += w*v.y;
    }
    *(float2*)(part + (size_t)bm*DQ + d0) = make_float2(a0,a1);
  }
}

// ---- LEAN GEMM: A pre-converted (xbf), pure gload_lds staging, no loop VALU.
__global__ __launch_bounds__(512, 4) void k_gate_lean(
    const short* __restrict__ xbf, const float* __restrict__ x,
    const short* __restrict__ w1t, const float* __restrict__ xqv,
    const float* __restrict__ wq, const float* __restrict__ w2,
    const float* __restrict__ b1, const float* __restrict__ b2p,
    const float* __restrict__ lamp,
    const void* __restrict__ maskp, const int* __restrict__ flag,
    const int* __restrict__ lens,
    float* __restrict__ part, float* __restrict__ wsum)
{
  __shared__ __align__(16) short As[2][BM*BK];   // 4KB x2
  __shared__ __align__(16) short Bs[2][BN*BK];   // 32KB x2
  __shared__ float red[8][BM];
  __shared__ float wrow[BM];

  int tid = threadIdx.x;
  int bm = blockIdx.x;
  int m0 = bm*BM;
  int batch = bm >> 5;
  int sBase = (bm & 31) * 64;
  int lane = tid & 63, wid = tid >> 6;
  int wn = wid;
  int lo = lane & 15, hi = lane >> 4;

  const short* bsrc = w1t + (size_t)(tid>>2)*DQ + (tid&3)*8;
  const short* asrc = xbf + (size_t)(m0 + (tid>>2))*DQ + (tid&3)*8; // tid<256

  float w2v[4], b1v[4];
  #pragma unroll
  for (int fn=0;fn<4;fn++){
    int n = wn*64 + fn*16 + lo;
    w2v[fn] = w2[n]; b1v[fn] = b1[n];
  }

  // prologue: stage k-chunk 0
  #pragma unroll
  for (int i=0;i<4;i++)
    gload_lds16(bsrc + (size_t)i*128*DQ, &Bs[0][i*4096 + tid*8]);
  if (tid < 256) gload_lds16(asrc, &As[0][tid*8]);
  __syncthreads();

  f32x4 acc[4][4];
  #pragma unroll
  for (int a=0;a<4;a++)
    #pragma unroll
    for (int b=0;b<4;b++) acc[a][b] = (f32x4){0.f,0.f,0.f,0.f};

  for (int t=0;t<32;t++){
    int cur = t & 1, nxt = cur ^ 1;
    int kn = (t+1)*BK;
    if (t < 31){
      #pragma unroll
      for (int i=0;i<4;i++)
        gload_lds16(bsrc + (size_t)i*128*DQ + kn, &Bs[nxt][i*4096 + tid*8]);
      if (tid < 256) gload_lds16(asrc + kn, &As[nxt][tid*8]);
    }
    bf16x8 af[4], bfr[4];
    #pragma unroll
    for (int fm=0;fm<4;fm++)
      af[fm] = *(const bf16x8*)(&As[cur][(fm*16+lo)*BK + hi*8]);
    #pragma unroll
    for (int fn=0;fn<4;fn++)
      bfr[fn] = *(const bf16x8*)(&Bs[cur][(wn*64+fn*16+lo)*BK + hi*8]);
    #pragma unroll
    for (int fm=0;fm<4;fm++)
      #pragma unroll
      for (int fn=0;fn<4;fn++)
        acc[fm][fn] = __builtin_amdgcn_mfma_f32_16x16x32_bf16(af[fm], bfr[fn], acc[fm][fn], 0,0,0);
    __syncthreads();
  }

  gate_epilogue(tid, wid, lo, hi, bm, m0, batch, sBase, acc, w2v, b1v,
                red, wrow, xqv, wq, b2p, lamp, maskp, flag, lens,
                x, part, wsum);
}

// ---- FALLBACK GEMM (round-7 champion): in-loop cvt + xq, f32 A from global.
__global__ __launch_bounds__(512) void k_gate_fb(
    const float* __restrict__ x, const short* __restrict__ w1t,
    const float* __restrict__ wq, const float* __restrict__ w2,
    const float* __restrict__ b1, const float* __restrict__ b2p,
    const float* __restrict__ lamp,
    const void* __restrict__ maskp, const int* __restrict__ flag,
    const int* __restrict__ lens,
    float* __restrict__ part, float* __restrict__ wsum, float* __restrict__ xqv)
{
  __shared__ __align__(16) short As[2][BM*BK];
  __shared__ __align__(16) short Bs[2][BN*BK];
  __shared__ float wqs[DQ];
  __shared__ float red[8][BM];
  __shared__ float wrow[BM];

  int tid = threadIdx.x;
  int bm = blockIdx.x;
  int m0 = bm*BM;
  int batch = bm >> 5;
  int sBase = (bm & 31) * 64;
  int lane = tid & 63, wid = tid >> 6;
  int wn = wid;
  int lo = lane & 15, hi = lane >> 4;

  wqs[tid] = wq[tid];
  if (tid < 512) wqs[tid+512] = wq[tid+512];

  int ar = tid >> 3, ac = (tid & 7) * 4;
  const float* asrc = x + (size_t)(m0 + ar)*DQ + ac;
  const short* bsrc = w1t + (size_t)(tid>>2)*DQ + (tid&3)*8;

  float w2v[4], b1v[4];
  #pragma unroll
  for (int fn=0;fn<4;fn++){
    int n = wn*64 + fn*16 + lo;
    w2v[fn] = w2[n]; b1v[fn] = b1[n];
  }

  f32x4 r0 = *(const f32x4*)(asrc);
  #pragma unroll
  for (int i=0;i<4;i++)
    gload_lds16(bsrc + (size_t)i*128*DQ, &Bs[0][i*4096 + tid*8]);
  __syncthreads();
  float xqacc = 0.f;
  {
    f32x4 w0 = *(const f32x4*)(wqs + ac);
    #pragma unroll
    for (int j=0;j<4;j++) xqacc += r0[j]*w0[j];
    bf16x4 s0v;
    #pragma unroll
    for (int j=0;j<4;j++) s0v[j]=f2bf(r0[j]);
    *(bf16x4*)(&As[0][ar*BK + ac]) = s0v;
  }
  __syncthreads();

  f32x4 acc[4][4];
  #pragma unroll
  for (int a=0;a<4;a++)
    #pragma unroll
    for (int b=0;b<4;b++) acc[a][b] = (f32x4){0.f,0.f,0.f,0.f};

  for (int t=0;t<32;t++){
    int cur = t & 1, nxt = cur ^ 1;
    int kn = (t+1)*BK;
    if (t < 31){
      r0 = *(const f32x4*)(asrc + kn);
      #pragma unroll
      for (int i=0;i<4;i++)
        gload_lds16(bsrc + (size_t)i*128*DQ + kn, &Bs[nxt][i*4096 + tid*8]);
    }
    bf16x8 af[4], bfr[4];
    #pragma unroll
    for (int fm=0;fm<4;fm++)
      af[fm] = *(const bf16x8*)(&As[cur][(fm*16+lo)*BK + hi*8]);
    #pragma unroll
    for (int fn=0;fn<4;fn++)
      bfr[fn] = *(const bf16x8*)(&Bs[cur][(wn*64+fn*16+lo)*BK + hi*8]);
    #pragma unroll
    for (int fm=0;fm<4;fm++)
      #pragma unroll
      for (int fn=0;fn<4;fn++)
        acc[fm][fn] = __builtin_amdgcn_mfma_f32_16x16x32_bf16(af[fm], bfr[fn], acc[fm][fn], 0,0,0);
    if (t < 31){
      f32x4 w0 = *(const f32x4*)(wqs + kn + ac);
      #pragma unroll
      for (int j=0;j<4;j++) xqacc += r0[j]*w0[j];
      bf16x4 s0v;
      #pragma unroll
      for (int j=0;j<4;j++) s0v[j]=f2bf(r0[j]);
      *(bf16x4*)(&As[nxt][ar*BK + ac]) = s0v;
    }
    __syncthreads();
  }

  {
    float s = xqacc;
    s += __shfl_xor(s,1); s += __shfl_xor(s,2); s += __shfl_xor(s,4);
    if ((tid & 7) == 0) xqv[m0 + ar] = s;
  }
  __syncthreads();

  gate_epilogue(tid, wid, lo, hi, bm, m0, batch, sBase, acc, w2v, b1v,
                red, wrow, xqv, wq, b2p, lamp, maskp, flag, lens,
                x, part, wsum);
}

// ---- final: out[b][d] = sum_c part[b*32+c][d] / sum_c wsum[b*32+c]
__global__ __launch_bounds__(256) void k_fin(const float* __restrict__ part,
                                             const float* __restrict__ wsum,
                                             float* __restrict__ out){
  int i = blockIdx.x*256 + threadIdx.x;   // 32768
  int b = i >> 10, d = i & 1023;
  float den = 0.f;
  #pragma unroll
  for (int c=0;c<32;c++) den += wsum[b*32+c];
  float s = 0.f;
  #pragma unroll
  for (int c=0;c<32;c++) s += part[((size_t)(b*32+c))*DQ + d];
  out[i] = s/den;
}

extern "C" void kernel_launch(void* const* d_in, const int* in_sizes, int n_in,
                              void* d_out, int out_size, void* d_ws, size_t ws_size,
                              hipStream_t stream)
{
  const float* x    = (const float*)d_in[0];
  const void*  mask = d_in[1];
  const float* w1   = (const float*)d_in[2];
  const float* b1   = (const float*)d_in[3];
  const float* w2   = (const float*)d_in[4];
  const float* b2   = (const float*)d_in[5];
  const float* lam  = (const float*)d_in[6];
  const float* q    = (const float*)d_in[7];
  const float* kw   = (const float*)d_in[8];
  const float* kb   = (const float*)d_in[9];
  char* ws = (char*)d_ws;
  short* w1t = (short*)ws;                               // 1 MB
  float* wq  = (float*)(ws + (1<<20));                   // 8 KB (1025 floats)
  int* flag  = (int*)(ws + (1<<20) + 8192);              // 4 B
  int* lens  = (int*)(ws + (1<<20) + 8448);              // 128 B
  float* wsum= (float*)(ws + (1<<20) + 12544);           // 4 KB
  float* xqv = (float*)(ws + (1<<20) + 32768);           // 256 KB
  float* part= (float*)(ws + (2<<20));                   // 4 MB
  short* xbf = (short*)(ws + (8ull<<20));                // 128 MB (lean path)
  float* out = (float*)d_out;

  const size_t NEEDED = (8ull<<20) + ((size_t)MQ*DQ*2);

  k_w1t<<<dim3((NQ*DQ+255)/256), 256, 0, stream>>>(w1, w1t);
  k_wq<<<dim3(DQ+1), 256, 0, stream>>>(kw, kb, q, wq);
  k_det<<<dim3(1), 256, 0, stream>>>((const unsigned int*)mask, flag);
  k_len<<<dim3(BQ), 256, 0, stream>>>(mask, flag, lens);

  if (ws_size >= NEEDED){
    k_xprep<<<dim3(MQ/2), 256, 0, stream>>>(x, wq, xbf, xqv);
    k_gate_lean<<<dim3(MQ/BM), 512, 0, stream>>>(xbf, x, w1t, xqv, wq, w2,
                                                 b1, b2, lam, mask, flag, lens,
                                                 part, wsum);
  } else {
    k_gate_fb<<<dim3(MQ/BM), 512, 0, stream>>>(x, w1t, wq, w2, b1, b2, lam,
                                               mask, flag, lens, part, wsum, xqv);
  }
  k_fin<<<dim3((BQ*DQ)/256), 256, 0, stream>>>(part, wsum, out);
}

// Round 12
// 187.091 us; speedup vs baseline: 1.5629x; 1.5629x over previous
//
#include <hip/hip_runtime.h>
#include <hip/hip_bf16.h>
#include <math.h>

#define BQ 32
#define SQ 2048
#define DQ 1024
#define NQ 512
#define MQ (BQ*SQ)
#define BM 128
#define BN 256
#define BK 32

typedef __attribute__((ext_vector_type(8))) short bf16x8;
typedef __attribute__((ext_vector_type(4))) float f32x4;

#define SB0 __builtin_amdgcn_sched_barrier(0)

// compiler-path f32->bf16 (RTNE, pairs into v_cvt_pk_bf16_f32)
__device__ __forceinline__ short f2bf(float f){
  return __builtin_bit_cast(short, __float2bfloat16(f));
}

__device__ __forceinline__ void gload_lds16(const void* g, void* l){
  __builtin_amdgcn_global_load_lds(
      (const __attribute__((address_space(1))) unsigned int*)g,
      (__attribute__((address_space(3))) unsigned int*)l, 16, 0, 0);
}

// ---- prep: transpose gate_w1 [K=1024][N=512] -> bf16 w1t [N=512][K=1024]
__global__ void k_w1t(const float* __restrict__ w1, short* __restrict__ w1t){
  int i = blockIdx.x*256 + threadIdx.x;
  if (i >= NQ*DQ) return;
  int n = i >> 10, k = i & (DQ-1);
  w1t[i] = f2bf(w1[(size_t)k*NQ + n]);
}

// ---- prep: wq[d] = key_w[d,:]·q (d<1024); wq[1024] = key_b·q
__global__ void k_wq(const float* __restrict__ kw, const float* __restrict__ kb,
                     const float* __restrict__ q, float* __restrict__ wq){
  __shared__ float sh[4];
  int d = blockIdx.x, t = threadIdx.x;
  const float* row = (d < DQ) ? (kw + (size_t)d*DQ) : kb;
  float s = 0.f;
  for (int e=t;e<DQ;e+=256) s += row[e]*q[e];
  #pragma unroll
  for (int o=32;o;o>>=1) s += __shfl_down(s,o);
  if ((t&63)==0) sh[t>>6]=s;
  __syncthreads();
  if (t==0) wq[d] = sh[0]+sh[1]+sh[2]+sh[3];
}

// ---- mask dtype detector: 0=int32(0/1), 1=float32(0/1.0f), 2=byte(bool)
__global__ void k_det(const unsigned int* __restrict__ m, int* __restrict__ flag){
  __shared__ int so, sf;
  int t = threadIdx.x;
  if (t==0){ so=0; sf=0; }
  __syncthreads();
  int o=0, f1=0;
  for (int i=t;i<MQ/4;i+=256){
    unsigned v = m[i];
    if (v==0x3F800000u) f1=1;
    else if (v>1u) o=1;
  }
  if (o) atomicOr(&so,1);
  if (f1) atomicOr(&sf,1);
  __syncthreads();
  if (t==0) *flag = so?2:(sf?1:0);
}

// ---- per-batch valid length
__global__ __launch_bounds__(256) void k_len(const void* __restrict__ maskp,
                                             const int* __restrict__ flag,
                                             int* __restrict__ lens){
  __shared__ int sh[4];
  int b = blockIdx.x, t = threadIdx.x;
  int fl = *flag;
  const unsigned char* m8 = (const unsigned char*)maskp;
  const float* mf = (const float*)maskp;
  const int* mi = (const int*)maskp;
  int cnt = 0;
  #pragma unroll
  for (int i=0;i<8;i++){
    size_t idx = (size_t)b*SQ + t + i*256;
    int mm = (fl==2) ? (m8[idx]!=0) : (fl==1) ? (mf[idx]!=0.0f) : (mi[idx]!=0);
    cnt += mm^1;
  }
  #pragma unroll
  for (int o=32;o;o>>=1) cnt += __shfl_down(cnt,o);
  if ((t&63)==0) sh[t>>6]=cnt;
  __syncthreads();
  if (t==0) lens[b] = sh[0]+sh[1]+sh[2]+sh[3];
}

// ---- h=x@W1 MFMA GEMM with no-drain barriers (raw s_barrier + lgkmcnt only).
// 128x256 tile, BK=32, 512 thr = 8 waves (2wm x 4wn), wave tile 64x64.
// B triple-buffered (loads span a step across barriers); A reg-staged
// issue-early/convert-late; xq fused in bn==0 blocks. XCD-chunked swizzle.
// Epilogue: GELU·w2 partials -> gpart[2][MQ]; xq -> xqv.
__global__ __launch_bounds__(512) void k_gate(
    const float* __restrict__ x, const short* __restrict__ w1t,
    const float* __restrict__ wq, const float* __restrict__ w2,
    const float* __restrict__ b1,
    float* __restrict__ gpart, float* __restrict__ xqv)
{
  __shared__ __align__(16) short As[2][BM*BK];   // 8KB x2
  __shared__ __align__(16) short Bs[3][BN*BK];   // 16KB x3
  __shared__ float wqs[DQ];                       // 4KB
  __shared__ float red[4][BM];                    // 2KB

  int tid = threadIdx.x;
  int phys = blockIdx.x;
  int bid = ((phys & 7) << 7) | (phys >> 3);     // 1024 blocks, XCD-chunked
  int bm = bid >> 1, bn = bid & 1;
  int m0 = bm*BM, n0 = bn*BN;
  int lane = tid & 63, wid = tid >> 6;
  int wm = wid >> 2, wn = wid & 3;
  int lo = lane & 15, hi = lane >> 4;

  wqs[tid]     = wq[tid];
  wqs[tid+512] = wq[tid+512];

  int ar = tid >> 2, acf = (tid & 3) * 8;
  const float* asrc = x + (size_t)(m0 + ar)*DQ + acf;
  const short* bsrc = w1t + (size_t)(n0 + (tid>>2))*DQ + (tid&3)*8;

  float w2v[4], b1v[4];
  #pragma unroll
  for (int fn=0;fn<4;fn++){
    int n = n0 + wn*64 + fn*16 + lo;
    w2v[fn] = w2[n]; b1v[fn] = b1[n];
  }

  // ---- prologue: stage B(0),B(1); A(0) via regs (auto vmcnt(0) drains all once)
  gload_lds16(bsrc,                       &Bs[0][tid*8]);
  gload_lds16(bsrc + (size_t)128*DQ,      &Bs[0][4096 + tid*8]);
  gload_lds16(bsrc + BK,                  &Bs[1][tid*8]);
  gload_lds16(bsrc + (size_t)128*DQ + BK, &Bs[1][4096 + tid*8]);
  f32x4 a0 = *(const f32x4*)(asrc);
  f32x4 a1 = *(const f32x4*)(asrc + 4);
  {
    bf16x8 sv;
    #pragma unroll
    for (int j=0;j<4;j++){ sv[j]=f2bf(a0[j]); sv[4+j]=f2bf(a1[j]); }
    *(bf16x8*)(&As[0][ar*BK + acf]) = sv;
  }
  asm volatile("s_waitcnt lgkmcnt(0)" ::: "memory");
  SB0;
  __builtin_amdgcn_s_barrier();
  SB0;
  float xqacc = 0.f;
  if (bn == 0){
    f32x4 w0 = *(const f32x4*)(wqs + acf);
    f32x4 w1f = *(const f32x4*)(wqs + acf + 4);
    #pragma unroll
    for (int j=0;j<4;j++) xqacc += a0[j]*w0[j] + a1[j]*w1f[j];
  }

  f32x4 acc[4][4];
  #pragma unroll
  for (int a=0;a<4;a++)
    #pragma unroll
    for (int b=0;b<4;b++) acc[a][b] = (f32x4){0.f,0.f,0.f,0.f};

  f32x4 na0, na1;
  for (int t=0; t<32; ++t){
    int curA = t & 1;
    int curB = t % 3;
    // A(t+1) issue-early (f32 regs; consumed late this step)
    if (t < 31){
      na0 = *(const f32x4*)(asrc + (t+1)*BK);
      na1 = *(const f32x4*)(asrc + (t+1)*BK + 4);
    }
    SB0;
    // B(t+2) issue (stays in flight across this step's barrier)
    if (t < 30){
      int nb = (t+2) % 3;
      const short* bk = bsrc + (t+2)*BK;
      gload_lds16(bk,                  &Bs[nb][tid*8]);
      gload_lds16(bk + (size_t)128*DQ, &Bs[nb][4096 + tid*8]);
    }
    SB0;
    // compute on buffers t (complete: proven by previous step's A-reg wait chain)
    bf16x8 af[4], bfr[4];
    #pragma unroll
    for (int fm=0;fm<4;fm++)
      af[fm] = *(const bf16x8*)(&As[curA][(wm*64+fm*16+lo)*BK + hi*8]);
    #pragma unroll
    for (int fn=0;fn<4;fn++){
      int r = wn*64 + fn*16 + lo;
      bfr[fn] = *(const bf16x8*)(&Bs[curB][(r>>7)*4096 + (r&127)*32 + hi*8]);
    }
    #pragma unroll
    for (int fm=0;fm<4;fm++)
      #pragma unroll
      for (int fn=0;fn<4;fn++)
        acc[fm][fn] = __builtin_amdgcn_mfma_f32_16x16x32_bf16(af[fm], bfr[fn], acc[fm][fn], 0,0,0);
    SB0;
    // A(t+1) convert-late (+fused xq); auto-wait here = vmcnt(2) -> B(t+1) done too
    if (t < 31){
      if (bn == 0){
        f32x4 w0 = *(const f32x4*)(wqs + (t+1)*BK + acf);
        f32x4 w1f = *(const f32x4*)(wqs + (t+1)*BK + acf + 4);
        #pragma unroll
        for (int j=0;j<4;j++) xqacc += na0[j]*w0[j] + na1[j]*w1f[j];
      }
      bf16x8 sv;
      #pragma unroll
      for (int j=0;j<4;j++){ sv[j]=f2bf(na0[j]); sv[4+j]=f2bf(na1[j]); }
      *(bf16x8*)(&As[curA^1][ar*BK + acf]) = sv;
    }
    asm volatile("s_waitcnt lgkmcnt(0)" ::: "memory");
    SB0;
    __builtin_amdgcn_s_barrier();
    SB0;
  }

  // xq: combine 4 threads per row
  if (bn == 0){
    float s = xqacc;
    s += __shfl_xor(s,1); s += __shfl_xor(s,2);
    if ((tid & 3) == 0) xqv[m0 + ar] = s;
  }

  // GELU + dot w2 over this wave's 64 cols -> per-row partial in red[wn]
  #pragma unroll
  for (int fm=0;fm<4;fm++){
    #pragma unroll
    for (int j=0;j<4;j++){
      float s = 0.f;
      #pragma unroll
      for (int fn=0;fn<4;fn++){
        float h = acc[fm][fn][j] + b1v[fn];
        float g = 0.5f*h*(1.0f + erff(h*0.70710678118f));
        s += g*w2v[fn];
      }
      s += __shfl_xor(s,1); s += __shfl_xor(s,2);
      s += __shfl_xor(s,4); s += __shfl_xor(s,8);
      if (lo == 0) red[wn][wm*64 + fm*16 + hi*4 + j] = s;
    }
  }
  __syncthreads();
  if (tid < BM){
    float g = red[0][tid] + red[1][tid] + red[2][tid] + red[3][tid];
    gpart[(size_t)bn*MQ + m0 + tid] = g;
  }
}

// ---- fused w-phase + pooling: 256 blocks x 256 rows.
__global__ __launch_bounds__(256) void k_wpool(
    const float* __restrict__ x, const float* __restrict__ gpart,
    const float* __restrict__ xqv, const float* __restrict__ wq,
    const float* __restrict__ b2p, const float* __restrict__ lamp,
    const void* __restrict__ maskp, const int* __restrict__ flag,
    const int* __restrict__ lens,
    float* __restrict__ part, float* __restrict__ wsumv)
{
  __shared__ float wrow[256];
  __shared__ float ssum[4];
  int blk = blockIdx.x, t = threadIdx.x;
  int batch = blk >> 3;
  int sBase = (blk & 7) * 256;
  size_t R0 = (size_t)blk * 256;
  {
    size_t r = R0 + t;
    float gsum = b2p[0] + gpart[r] + gpart[(size_t)MQ + r];
    float gate = 1.0f/(1.0f+expf(-gsum));
    float qb = wq[DQ];
    float lg = (gate*xqv[r] + qb)*0.03125f;
    float lam = lamp[0];
    float posl = fmaxf(lam,0.f) + log1pf(expf(-fabsf(lam)));
    int L = lens[batch];
    int s = sBase + t;
    float pen = fmaxf((float)L - 1.0f - (float)s, 0.0f);
    int fl = *flag;
    size_t mi_ = (size_t)batch*SQ + s;
    int mm = (fl==2) ? (((const unsigned char*)maskp)[mi_]!=0)
           : (fl==1) ? (((const float*)maskp)[mi_]!=0.0f)
                     : (((const int*)maskp)[mi_]!=0);
    float e = mm ? 0.0f : expf(lg - posl*pen);
    wrow[t] = e*gate;
    float ts = e;
    #pragma unroll
    for (int o=1;o<64;o<<=1) ts += __shfl_xor(ts,o);
    if ((t&63)==0) ssum[t>>6] = ts;
  }
  __syncthreads();
  if (t==0) wsumv[blk] = ssum[0]+ssum[1]+ssum[2]+ssum[3];

  int d0 = t*4;
  const float* xb = x + R0*DQ + d0;
  f32x4 a = {0.f,0.f,0.f,0.f};
  #pragma unroll 8
  for (int s=0;s<256;s++){
    float w = wrow[s];
    f32x4 v = *(const f32x4*)(xb + (size_t)s*DQ);
    a[0] += w*v[0]; a[1] += w*v[1]; a[2] += w*v[2]; a[3] += w*v[3];
  }
  *(f32x4*)(part + (size_t)blk*DQ + d0) = a;
}

// ---- final: out[b][d] = sum_c part[b*8+c][d] / sum_c wsum[b*8+c]
__global__ __launch_bounds__(256) void k_fin(const float* __restrict__ part,
                                             const float* __restrict__ wsumv,
                                             float* __restrict__ out){
  int i = blockIdx.x*256 + threadIdx.x;   // 32768
  int b = i >> 10, d = i & 1023;
  float den = 0.f;
  #pragma unroll
  for (int c=0;c<8;c++) den += wsumv[b*8+c];
  float s = 0.f;
  #pragma unroll
  for (int c=0;c<8;c++) s += part[((size_t)(b*8+c))*DQ + d];
  out[i] = s/den;
}

extern "C" void kernel_launch(void* const* d_in, const int* in_sizes, int n_in,
                              void* d_out, int out_size, void* d_ws, size_t ws_size,
                              hipStream_t stream)
{
  const float* x    = (const float*)d_in[0];
  const void*  mask = d_in[1];
  const float* w1   = (const float*)d_in[2];
  const float* b1   = (const float*)d_in[3];
  const float* w2   = (const float*)d_in[4];
  const float* b2   = (const float*)d_in[5];
  const float* lam  = (const float*)d_in[6];
  const float* q    = (const float*)d_in[7];
  const float* kw   = (const float*)d_in[8];
  const float* kb   = (const float*)d_in[9];
  char* ws = (char*)d_ws;
  short* w1t   = (short*)ws;                             // 1 MB
  float* wq    = (float*)(ws + (1<<20));                 // 8 KB (1025 floats)
  int*   flag  = (int*)(ws + (1<<20) + 8192);            // 4 B
  int*   lens  = (int*)(ws + (1<<20) + 8448);            // 128 B
  float* wsumv = (float*)(ws + (1<<20) + 12544);         // 1 KB (256)
  float* xqv   = (float*)(ws + (1<<20) + 32768);         // 256 KB
  float* gpart = (float*)(ws + (2<<20));                 // 512 KB (2 x MQ)
  float* part  = (float*)(ws + (3<<20));                 // 1 MB (256 x 1024)
  float* out   = (float*)d_out;

  k_w1t<<<dim3((NQ*DQ+255)/256), 256, 0, stream>>>(w1, w1t);
  k_wq<<<dim3(DQ+1), 256, 0, stream>>>(kw, kb, q, wq);
  k_det<<<dim3(1), 256, 0, stream>>>((const unsigned int*)mask, flag);
  k_len<<<dim3(BQ), 256, 0, stream>>>(mask, flag, lens);
  k_gate<<<dim3((MQ/BM)*(NQ/BN)), 512, 0, stream>>>(x, w1t, wq, w2, b1,
                                                    gpart, xqv);
  k_wpool<<<dim3(MQ/256), 256, 0, stream>>>(x, gpart, xqv, wq, b2, lam,
                                            mask, flag, lens, part, wsumv);
  k_fin<<<dim3((BQ*DQ)/256), 256, 0, stream>>>(part, wsumv, out);
}

// Round 13
// 186.027 us; speedup vs baseline: 1.5718x; 1.0057x over previous
//
#include <hip/hip_runtime.h>
#include <hip/hip_bf16.h>
#include <math.h>

#define BQ 32
#define SQ 2048
#define DQ 1024
#define NQ 512
#define MQ (BQ*SQ)
#define BM 128
#define BN 256
#define BK 32

typedef __attribute__((ext_vector_type(8))) short bf16x8;
typedef __attribute__((ext_vector_type(4))) float f32x4;

// compiler-path f32->bf16 (RTNE, pairs into v_cvt_pk_bf16_f32)
__device__ __forceinline__ short f2bf(float f){
  return __builtin_bit_cast(short, __float2bfloat16(f));
}

__device__ __forceinline__ void gload_lds16(const void* g, void* l){
  __builtin_amdgcn_global_load_lds(
      (const __attribute__((address_space(1))) unsigned int*)g,
      (__attribute__((address_space(3))) unsigned int*)l, 16, 0, 0);
}

// ---- prep: transpose gate_w1 [K=1024][N=512] -> bf16 w1t [N=512][K=1024]
__global__ void k_w1t(const float* __restrict__ w1, short* __restrict__ w1t){
  int i = blockIdx.x*256 + threadIdx.x;
  if (i >= NQ*DQ) return;
  int n = i >> 10, k = i & (DQ-1);
  w1t[i] = f2bf(w1[(size_t)k*NQ + n]);
}

// ---- prep: wq[d] = key_w[d,:]·q (d<1024); wq[1024] = key_b·q
__global__ void k_wq(const float* __restrict__ kw, const float* __restrict__ kb,
                     const float* __restrict__ q, float* __restrict__ wq){
  __shared__ float sh[4];
  int d = blockIdx.x, t = threadIdx.x;
  const float* row = (d < DQ) ? (kw + (size_t)d*DQ) : kb;
  float s = 0.f;
  for (int e=t;e<DQ;e+=256) s += row[e]*q[e];
  #pragma unroll
  for (int o=32;o;o>>=1) s += __shfl_down(s,o);
  if ((t&63)==0) sh[t>>6]=s;
  __syncthreads();
  if (t==0) wq[d] = sh[0]+sh[1]+sh[2]+sh[3];
}

// ---- mask dtype detector: 0=int32(0/1), 1=float32(0/1.0f), 2=byte(bool)
__global__ void k_det(const unsigned int* __restrict__ m, int* __restrict__ flag){
  __shared__ int so, sf;
  int t = threadIdx.x;
  if (t==0){ so=0; sf=0; }
  __syncthreads();
  int o=0, f1=0;
  for (int i=t;i<MQ/4;i+=256){
    unsigned v = m[i];
    if (v==0x3F800000u) f1=1;
    else if (v>1u) o=1;
  }
  if (o) atomicOr(&so,1);
  if (f1) atomicOr(&sf,1);
  __syncthreads();
  if (t==0) *flag = so?2:(sf?1:0);
}

// ---- per-batch valid length
__global__ __launch_bounds__(256) void k_len(const void* __restrict__ maskp,
                                             const int* __restrict__ flag,
                                             int* __restrict__ lens){
  __shared__ int sh[4];
  int b = blockIdx.x, t = threadIdx.x;
  int fl = *flag;
  const unsigned char* m8 = (const unsigned char*)maskp;
  const float* mf = (const float*)maskp;
  const int* mi = (const int*)maskp;
  int cnt = 0;
  #pragma unroll
  for (int i=0;i<8;i++){
    size_t idx = (size_t)b*SQ + t + i*256;
    int mm = (fl==2) ? (m8[idx]!=0) : (fl==1) ? (mf[idx]!=0.0f) : (mi[idx]!=0);
    cnt += mm^1;
  }
  #pragma unroll
  for (int o=32;o;o>>=1) cnt += __shfl_down(cnt,o);
  if ((t&63)==0) sh[t>>6]=cnt;
  __syncthreads();
  if (t==0) lens[b] = sh[0]+sh[1]+sh[2]+sh[3];
}

// ---- fused MFMA GEMM (r5 champion): h=x@W1 bf16, LDS double-buffered,
// epilogue GELU·w2 partials -> gpart[8][MQ]; xq fused in A staging (bn==0).
// 128x256 tile, BK=32, 512 threads = 8 waves (2 wm x 4 wn), wave tile 64x64.
// Chunked XCD remap: both bn-blocks of each bm land on one XCD's L2.
__global__ __launch_bounds__(512) void k_gate(
    const float* __restrict__ x, const short* __restrict__ w1t,
    const float* __restrict__ wq, const float* __restrict__ w2,
    const float* __restrict__ b1,
    float* __restrict__ gpart, float* __restrict__ xq)
{
  __shared__ __align__(16) short As[2][BM*BK];   // 8KB x2
  __shared__ __align__(16) short Bs[2][BN*BK];   // 16KB x2
  __shared__ float wqs[DQ];                       // 4KB

  int tid = threadIdx.x;
  int phys = blockIdx.x;
  // 1024 blocks, 8 XCDs round-robin by phys%8 -> logical chunks of 128/XCD
  int bid = ((phys & 7) << 7) | (phys >> 3);
  int bm = bid >> 1, bn = bid & 1;
  int m0 = bm*BM;
  int lane = tid & 63, wid = tid >> 6;
  int wm = wid >> 2, wn = wid & 3;
  int lo = lane & 15, hi = lane >> 4;

  wqs[tid]     = wq[tid];
  wqs[tid+512] = wq[tid+512];

  // A staging map: thread t -> row t>>2 (0..127), cols (t&3)*8 .. +8
  int ar = tid >> 2, ac = (tid & 3) * 8;
  const float* asrc = x + (size_t)(m0 + ar)*DQ + ac;
  // B staging: issue i covers tile rows i*128+(t>>2); LDS shorts i*4096 + t*8
  const short* bsrc = w1t + (size_t)(bn*BN + (tid>>2))*DQ + (tid&3)*8;

  float w2v[4], b1v[4];
  #pragma unroll
  for (int fn=0;fn<4;fn++){
    int n = bn*BN + wn*64 + fn*16 + lo;
    w2v[fn] = w2[n]; b1v[fn] = b1[n];
  }

  // ---- prologue: stage k0=0
  f32x4 r0 = *(const f32x4*)(asrc);
  f32x4 r1 = *(const f32x4*)(asrc + 4);
  gload_lds16(bsrc,                    &Bs[0][tid*8]);
  gload_lds16(bsrc + (size_t)128*DQ,   &Bs[0][tid*8 + 4096]);
  __syncthreads();   // wqs visible; Bs[0] drained (barrier implies vmcnt(0))
  float xqacc = 0.f;
  {
    if (bn == 0){
      f32x4 w0 = *(const f32x4*)(wqs + ac);
      f32x4 w1v = *(const f32x4*)(wqs + ac + 4);
      #pragma unroll
      for (int j=0;j<4;j++)
        xqacc += r0[j]*w0[j] + r1[j]*w1v[j];
    }
    bf16x8 s0;
    #pragma unroll
    for (int j=0;j<4;j++){ s0[j]=f2bf(r0[j]); s0[4+j]=f2bf(r1[j]); }
    *(bf16x8*)(&As[0][ar*BK + ac]) = s0;
  }
  __syncthreads();

  f32x4 acc[4][4];
  #pragma unroll
  for (int a=0;a<4;a++)
    #pragma unroll
    for (int b=0;b<4;b++) acc[a][b] = (f32x4){0.f,0.f,0.f,0.f};

  for (int t=0;t<32;t++){
    int cur = t & 1, nxt = cur ^ 1;
    int k0n = (t+1)*BK;
    if (t < 31){
      r0 = *(const f32x4*)(asrc + k0n);
      r1 = *(const f32x4*)(asrc + k0n + 4);
      gload_lds16(bsrc + k0n,                  &Bs[nxt][tid*8]);
      gload_lds16(bsrc + (size_t)128*DQ + k0n, &Bs[nxt][tid*8 + 4096]);
    }
    bf16x8 af[4], bfr[4];
    #pragma unroll
    for (int fm=0;fm<4;fm++)
      af[fm] = *(const bf16x8*)(&As[cur][(wm*64+fm*16+lo)*BK + hi*8]);
    #pragma unroll
    for (int fn=0;fn<4;fn++)
      bfr[fn] = *(const bf16x8*)(&Bs[cur][(wn*64+fn*16+lo)*BK + hi*8]);
    #pragma unroll
    for (int fm=0;fm<4;fm++)
      #pragma unroll
      for (int fn=0;fn<4;fn++)
        acc[fm][fn] = __builtin_amdgcn_mfma_f32_16x16x32_bf16(af[fm], bfr[fn], acc[fm][fn], 0,0,0);
    if (t < 31){
      if (bn == 0){
        f32x4 w0 = *(const f32x4*)(wqs + k0n + ac);
        f32x4 w1v = *(const f32x4*)(wqs + k0n + ac + 4);
        #pragma unroll
        for (int j=0;j<4;j++)
          xqacc += r0[j]*w0[j] + r1[j]*w1v[j];
      }
      bf16x8 s0;
      #pragma unroll
      for (int j=0;j<4;j++){ s0[j]=f2bf(r0[j]); s0[4+j]=f2bf(r1[j]); }
      *(bf16x8*)(&As[nxt][ar*BK + ac]) = s0;
    }
    __syncthreads();
  }

  // xq: combine the 4 threads per row
  if (bn == 0){
    float s = xqacc;
    s += __shfl_xor(s, 1);
    s += __shfl_xor(s, 2);
    if ((tid & 3) == 0) xq[m0 + ar] = s;
  }

  // epilogue: GELU + dot w2 over this wave's 64 cols -> per-row partial strip
  #pragma unroll
  for (int fm=0;fm<4;fm++){
    #pragma unroll
    for (int j=0;j<4;j++){
      float s = 0.f;
      #pragma unroll
      for (int fn=0;fn<4;fn++){
        float h = acc[fm][fn][j] + b1v[fn];
        float g = 0.5f*h*(1.0f + erff(h*0.70710678118f));
        s += g*w2v[fn];
      }
      s += __shfl_xor(s,1); s += __shfl_xor(s,2);
      s += __shfl_xor(s,4); s += __shfl_xor(s,8);
      if (lo == 0){
        int p = bn*4 + wn;
        gpart[(size_t)p*MQ + m0 + wm*64 + fm*16 + hi*4 + j] = s;
      }
    }
  }
}

// ---- fused w-phase + pooling: 256 blocks x 256 rows.
__global__ __launch_bounds__(256) void k_wpool(
    const float* __restrict__ x, const float* __restrict__ gpart,
    const float* __restrict__ xqv, const float* __restrict__ wq,
    const float* __restrict__ b2p, const float* __restrict__ lamp,
    const void* __restrict__ maskp, const int* __restrict__ flag,
    const int* __restrict__ lens,
    float* __restrict__ part, float* __restrict__ wsumv)
{
  __shared__ float wrow[256];
  __shared__ float ssum[4];
  int blk = blockIdx.x, t = threadIdx.x;
  int batch = blk >> 3;
  int sBase = (blk & 7) * 256;
  size_t R0 = (size_t)blk * 256;
  {
    size_t r = R0 + t;
    float gsum = b2p[0];
    #pragma unroll
    for (int p=0;p<8;p++) gsum += gpart[(size_t)p*MQ + r];
    float gate = 1.0f/(1.0f+expf(-gsum));
    float qb = wq[DQ];
    float lg = (gate*xqv[r] + qb)*0.03125f;
    float lam = lamp[0];
    float posl = fmaxf(lam,0.f) + log1pf(expf(-fabsf(lam)));
    int L = lens[batch];
    int s = sBase + t;
    float pen = fmaxf((float)L - 1.0f - (float)s, 0.0f);
    int fl = *flag;
    size_t mi_ = (size_t)batch*SQ + s;
    int mm = (fl==2) ? (((const unsigned char*)maskp)[mi_]!=0)
           : (fl==1) ? (((const float*)maskp)[mi_]!=0.0f)
                     : (((const int*)maskp)[mi_]!=0);
    float e = mm ? 0.0f : expf(lg - posl*pen);   // softmax denominator term
    wrow[t] = e*gate;                             // pooling weight
    float ts = e;
    #pragma unroll
    for (int o=1;o<64;o<<=1) ts += __shfl_xor(ts,o);
    if ((t&63)==0) ssum[t>>6] = ts;
  }
  __syncthreads();
  if (t==0) wsumv[blk] = ssum[0]+ssum[1]+ssum[2]+ssum[3];

  int d0 = t*4;
  const float* xb = x + R0*DQ + d0;
  f32x4 a = {0.f,0.f,0.f,0.f};
  #pragma unroll 8
  for (int s=0;s<256;s++){
    float w = wrow[s];
    f32x4 v = *(const f32x4*)(xb + (size_t)s*DQ);
    a[0] += w*v[0]; a[1] += w*v[1]; a[2] += w*v[2]; a[3] += w*v[3];
  }
  *(f32x4*)(part + (size_t)blk*DQ + d0) = a;
}

// ---- final: out[b][d] = sum_c part[b*8+c][d] / sum_c wsum[b*8+c]
__global__ __launch_bounds__(256) void k_fin(const float* __restrict__ part,
                                             const float* __restrict__ wsumv,
                                             float* __restrict__ out){
  int i = blockIdx.x*256 + threadIdx.x;   // 32768
  int b = i >> 10, d = i & 1023;
  float den = 0.f;
  #pragma unroll
  for (int c=0;c<8;c++) den += wsumv[b*8+c];
  float s = 0.f;
  #pragma unroll
  for (int c=0;c<8;c++) s += part[((size_t)(b*8+c))*DQ + d];
  out[i] = s/den;
}

extern "C" void kernel_launch(void* const* d_in, const int* in_sizes, int n_in,
                              void* d_out, int out_size, void* d_ws, size_t ws_size,
                              hipStream_t stream)
{
  const float* x    = (const float*)d_in[0];
  const void*  mask = d_in[1];
  const float* w1   = (const float*)d_in[2];
  const float* b1   = (const float*)d_in[3];
  const float* w2   = (const float*)d_in[4];
  const float* b2   = (const float*)d_in[5];
  const float* lam  = (const float*)d_in[6];
  const float* q    = (const float*)d_in[7];
  const float* kw   = (const float*)d_in[8];
  const float* kb   = (const float*)d_in[9];
  char* ws = (char*)d_ws;
  short* w1t   = (short*)ws;                             // 1 MB
  float* wq    = (float*)(ws + (1<<20));                 // 8 KB (1025 floats)
  int*   flag  = (int*)(ws + (1<<20) + 8192);            // 4 B
  int*   lens  = (int*)(ws + (1<<20) + 8448);            // 128 B
  float* wsumv = (float*)(ws + (1<<20) + 12544);         // 1 KB (256)
  float* xqv   = (float*)(ws + (1<<20) + 32768);         // 256 KB
  float* gpart = (float*)(ws + (2<<20));                 // 2 MB (8 x MQ)
  float* part  = (float*)(ws + (4<<20));                 // 1 MB (256 x 1024)
  float* out   = (float*)d_out;

  k_w1t<<<dim3((NQ*DQ+255)/256), 256, 0, stream>>>(w1, w1t);
  k_wq<<<dim3(DQ+1), 256, 0, stream>>>(kw, kb, q, wq);
  k_det<<<dim3(1), 256, 0, stream>>>((const unsigned int*)mask, flag);
  k_len<<<dim3(BQ), 256, 0, stream>>>(mask, flag, lens);
  k_gate<<<dim3((MQ/BM)*(NQ/BN)), 512, 0, stream>>>(x, w1t, wq, w2, b1,
                                                    gpart, xqv);
  k_wpool<<<dim3(MQ/256), 256, 0, stream>>>(x, gpart, xqv, wq, b2, lam,
                                            mask, flag, lens, part, wsumv);
  k_fin<<<dim3((BQ*DQ)/256), 256, 0, stream>>>(part, wsumv, out);
}